// Round 1
// baseline (580.886 us; speedup 1.0000x reference)
//
#include <hip/hip_runtime.h>
#include <stdint.h>

// HashEncoder (Instant-NGP / HashNeRF): 1M points, 16 levels, 2 feats, 2^19 table.
// Level-major gather kernel (keeps one 4MiB table per XCD-L2 window) + transpose.

static constexpr int NP = 1048576;
static constexpr int NL = 16;
static constexpr int TPB = 256;
static constexpr uint32_t HMASK = (1u << 19) - 1u;

// res_i = floor(16 * b^i), b = f32(exp((ln512-ln16)/15)) = 1.2599210739135742 (> 2^(1/3))
// -> power-of-two levels floor UP-side: 32/64/128/256/512. See round journal for ulp analysis.
__constant__ float c_res[NL] = {16.f, 20.f, 25.f, 32.f, 40.f, 50.f, 64.f, 80.f,
                                101.f, 128.f, 161.f, 203.f, 256.f, 322.f, 406.f, 512.f};

__device__ __forceinline__ float2 enc_one(
    float x0, float x1, float x2,
    float b0, float b1, float b2,
    float B0, float B1, float B2,
    const float2* __restrict__ tab, float res, float gate)
{
    // index path must be bit-exact vs numpy f32: sub/div/floor only (no contraction possible)
    float g0 = (B0 - b0) / res;
    float g1 = (B1 - b1) / res;
    float g2 = (B2 - b2) / res;
    float xc0 = fminf(fmaxf(x0, b0), B0);
    float xc1 = fminf(fmaxf(x1, b1), B1);
    float xc2 = fminf(fmaxf(x2, b2), B2);
    float f0 = floorf((xc0 - b0) / g0);
    float f1 = floorf((xc1 - b1) / g1);
    float f2 = floorf((xc2 - b2) / g2);
    // interpolation weights use RAW x (per reference); rounding here is ~1e-11 on output
    float v0 = f0 * g0 + b0;
    float v1 = f1 * g1 + b1;
    float v2 = f2 * g2 + b2;
    float w0 = (x0 - v0) / ((v0 + g0) - v0);
    float w1 = (x1 - v1) / ((v1 + g1) - v1);
    float w2 = (x2 - v2) / ((v2 + g2) - v2);

    uint32_t u0 = (uint32_t)(int)f0;
    uint32_t u1 = (uint32_t)(int)f1;
    uint32_t u2 = (uint32_t)(int)f2;
    uint32_t ya = u1 * 2654435761u, yb = (u1 + 1u) * 2654435761u;
    uint32_t za = u2 * 805459861u,  zb = (u2 + 1u) * 805459861u;
    uint32_t xa = u0, xb = u0 + 1u;

    // corner index = i*4 + j*2 + k (i on x, j on y, k on z)
    float2 e000 = tab[(xa ^ ya ^ za) & HMASK];
    float2 e001 = tab[(xa ^ ya ^ zb) & HMASK];
    float2 e010 = tab[(xa ^ yb ^ za) & HMASK];
    float2 e011 = tab[(xa ^ yb ^ zb) & HMASK];
    float2 e100 = tab[(xb ^ ya ^ za) & HMASK];
    float2 e101 = tab[(xb ^ ya ^ zb) & HMASK];
    float2 e110 = tab[(xb ^ yb ^ za) & HMASK];
    float2 e111 = tab[(xb ^ yb ^ zb) & HMASK];

    float s0 = 1.f - w0, s1 = 1.f - w1, s2 = 1.f - w2;
    // blend x
    float cx00x = e000.x * s0 + e100.x * w0, cx00y = e000.y * s0 + e100.y * w0;
    float cx01x = e001.x * s0 + e101.x * w0, cx01y = e001.y * s0 + e101.y * w0;
    float cx10x = e010.x * s0 + e110.x * w0, cx10y = e010.y * s0 + e110.y * w0;
    float cx11x = e011.x * s0 + e111.x * w0, cx11y = e011.y * s0 + e111.y * w0;
    // blend y
    float c0x = cx00x * s1 + cx10x * w1, c0y = cx00y * s1 + cx10y * w1;
    float c1x = cx01x * s1 + cx11x * w1, c1y = cx01y * s1 + cx11y * w1;
    // blend z
    float ox = c0x * s2 + c1x * w2;
    float oy = c0y * s2 + c1y * w2;
    return make_float2(ox * gate, oy * gate);
}

// Kernel 1: thread = (point, level). blockIdx.y = level -> level-major dispatch order,
// each XCD L2 holds ~one 4MiB table at a time. ws layout [level][point][2] coalesced.
__global__ __launch_bounds__(TPB) void k_enc(
    const float* __restrict__ x, const float* __restrict__ emb,
    const float* __restrict__ lw, const float* __restrict__ bmin,
    const float* __restrict__ bmax, float2* __restrict__ ws)
{
    int p = blockIdx.x * TPB + threadIdx.x;
    int l = blockIdx.y;
    float x0 = x[3 * p + 0], x1 = x[3 * p + 1], x2 = x[3 * p + 2];
    float b0 = bmin[0], b1 = bmin[1], b2 = bmin[2];
    float B0 = bmax[0], B1 = bmax[1], B2 = bmax[2];
    float res = c_res[l];
    float gate = 1.0f / (1.0f + __expf(0.f) * expf(-lw[l]));  // plain sigmoid
    gate = 1.0f / (1.0f + expf(-lw[l]));
    const float2* tab = (const float2*)(emb + ((size_t)l << 20));  // 2^19 entries * 2 floats
    float2 r = enc_one(x0, x1, x2, b0, b1, b2, B0, B1, B2, tab, res, gate);
    ws[(size_t)l * NP + p] = r;
}

// Kernel 2: transpose ws [16][N][2] -> out [N][32]. Coalesced float2 reads per level,
// 8x float4 contiguous 128B write per point (L2 write-combines across the wave).
__global__ __launch_bounds__(TPB) void k_tr(
    const float2* __restrict__ ws, float4* __restrict__ out)
{
    int p = blockIdx.x * TPB + threadIdx.x;
    float2 v[NL];
#pragma unroll
    for (int l = 0; l < NL; ++l) v[l] = ws[(size_t)l * NP + p];
#pragma unroll
    for (int j = 0; j < 8; ++j) {
        out[(size_t)p * 8 + j] =
            make_float4(v[2 * j].x, v[2 * j].y, v[2 * j + 1].x, v[2 * j + 1].y);
    }
}

// Fallback if ws is too small: thread = (point, group of 4 consecutive levels),
// writes one full 32B sector of out directly.
__global__ __launch_bounds__(TPB) void k_fused(
    const float* __restrict__ x, const float* __restrict__ emb,
    const float* __restrict__ lw, const float* __restrict__ bmin,
    const float* __restrict__ bmax, float* __restrict__ out)
{
    int p = blockIdx.x * TPB + threadIdx.x;
    int g = blockIdx.y;  // 0..3
    float x0 = x[3 * p + 0], x1 = x[3 * p + 1], x2 = x[3 * p + 2];
    float b0 = bmin[0], b1 = bmin[1], b2 = bmin[2];
    float B0 = bmax[0], B1 = bmax[1], B2 = bmax[2];
    float2 o[4];
#pragma unroll
    for (int m = 0; m < 4; ++m) {
        int l = g * 4 + m;
        float res = c_res[l];
        float gate = 1.0f / (1.0f + expf(-lw[l]));
        const float2* tab = (const float2*)(emb + ((size_t)l << 20));
        o[m] = enc_one(x0, x1, x2, b0, b1, b2, B0, B1, B2, tab, res, gate);
    }
    float4* op = (float4*)(out + (size_t)p * 32 + g * 8);
    op[0] = make_float4(o[0].x, o[0].y, o[1].x, o[1].y);
    op[1] = make_float4(o[2].x, o[2].y, o[3].x, o[3].y);
}

extern "C" void kernel_launch(void* const* d_in, const int* in_sizes, int n_in,
                              void* d_out, int out_size, void* d_ws, size_t ws_size,
                              hipStream_t stream) {
    const float* x    = (const float*)d_in[0];
    const float* emb  = (const float*)d_in[1];
    const float* lw   = (const float*)d_in[2];
    const float* bmin = (const float*)d_in[3];
    const float* bmax = (const float*)d_in[4];
    float* out = (float*)d_out;

    const size_t ws_need = (size_t)NL * NP * 2 * sizeof(float);  // 128 MB
    if (ws_size >= ws_need) {
        dim3 grid1(NP / TPB, NL);
        k_enc<<<grid1, TPB, 0, stream>>>(x, emb, lw, bmin, bmax, (float2*)d_ws);
        k_tr<<<NP / TPB, TPB, 0, stream>>>((const float2*)d_ws, (float4*)out);
    } else {
        dim3 grid(NP / TPB, 4);
        k_fused<<<grid, TPB, 0, stream>>>(x, emb, lw, bmin, bmax, out);
    }
}

// Round 2
// 556.443 us; speedup vs baseline: 1.0439x; 1.0439x over previous
//
#include <hip/hip_runtime.h>
#include <stdint.h>

// HashEncoder (Instant-NGP / HashNeRF): 1M points, 16 levels, 2 feats, 2^19 table.
// Level-major gather kernel (keeps one 4MiB table per XCD-L2 window) + direct
// line-efficient transpose (no LDS).

static constexpr int NP = 1048576;
static constexpr int NL = 16;
static constexpr int TPB = 256;
static constexpr uint32_t HMASK = (1u << 19) - 1u;

// res_i = floor(16 * b^i), b = f32(exp((ln512-ln16)/15)) = 1.2599210739135742 (> 2^(1/3))
// -> power-of-two levels floor on the UP side: 32/64/128/256/512. Verified R1: absmax 2.4e-7.
__constant__ float c_res[NL] = {16.f, 20.f, 25.f, 32.f, 40.f, 50.f, 64.f, 80.f,
                                101.f, 128.f, 161.f, 203.f, 256.f, 322.f, 406.f, 512.f};

__device__ __forceinline__ float2 enc_one(
    float x0, float x1, float x2,
    float b0, float b1, float b2,
    float B0, float B1, float B2,
    const float2* __restrict__ tab, float res, float gate)
{
    // index path must be bit-exact vs numpy f32: sub/div/floor only (no contraction possible)
    float g0 = (B0 - b0) / res;
    float g1 = (B1 - b1) / res;
    float g2 = (B2 - b2) / res;
    float xc0 = fminf(fmaxf(x0, b0), B0);
    float xc1 = fminf(fmaxf(x1, b1), B1);
    float xc2 = fminf(fmaxf(x2, b2), B2);
    float f0 = floorf((xc0 - b0) / g0);
    float f1 = floorf((xc1 - b1) / g1);
    float f2 = floorf((xc2 - b2) / g2);
    // interpolation weights use RAW x (per reference); rounding here is ~1e-11 on output
    float v0 = f0 * g0 + b0;
    float v1 = f1 * g1 + b1;
    float v2 = f2 * g2 + b2;
    float w0 = (x0 - v0) / ((v0 + g0) - v0);
    float w1 = (x1 - v1) / ((v1 + g1) - v1);
    float w2 = (x2 - v2) / ((v2 + g2) - v2);

    uint32_t u0 = (uint32_t)(int)f0;
    uint32_t u1 = (uint32_t)(int)f1;
    uint32_t u2 = (uint32_t)(int)f2;
    uint32_t ya = u1 * 2654435761u, yb = (u1 + 1u) * 2654435761u;
    uint32_t za = u2 * 805459861u,  zb = (u2 + 1u) * 805459861u;
    uint32_t xa = u0, xb = u0 + 1u;

    // corner index = i*4 + j*2 + k (i on x, j on y, k on z)
    float2 e000 = tab[(xa ^ ya ^ za) & HMASK];
    float2 e001 = tab[(xa ^ ya ^ zb) & HMASK];
    float2 e010 = tab[(xa ^ yb ^ za) & HMASK];
    float2 e011 = tab[(xa ^ yb ^ zb) & HMASK];
    float2 e100 = tab[(xb ^ ya ^ za) & HMASK];
    float2 e101 = tab[(xb ^ ya ^ zb) & HMASK];
    float2 e110 = tab[(xb ^ yb ^ za) & HMASK];
    float2 e111 = tab[(xb ^ yb ^ zb) & HMASK];

    float s0 = 1.f - w0, s1 = 1.f - w1, s2 = 1.f - w2;
    // blend x
    float cx00x = e000.x * s0 + e100.x * w0, cx00y = e000.y * s0 + e100.y * w0;
    float cx01x = e001.x * s0 + e101.x * w0, cx01y = e001.y * s0 + e101.y * w0;
    float cx10x = e010.x * s0 + e110.x * w0, cx10y = e010.y * s0 + e110.y * w0;
    float cx11x = e011.x * s0 + e111.x * w0, cx11y = e011.y * s0 + e111.y * w0;
    // blend y
    float c0x = cx00x * s1 + cx10x * w1, c0y = cx00y * s1 + cx10y * w1;
    float c1x = cx01x * s1 + cx11x * w1, c1y = cx01y * s1 + cx11y * w1;
    // blend z
    float ox = c0x * s2 + c1x * w2;
    float oy = c0y * s2 + c1y * w2;
    return make_float2(ox * gate, oy * gate);
}

// Kernel 1: thread = (point, level). blockIdx.y = level -> level-major dispatch order,
// each XCD L2 holds ~one 4MiB table at a time. ws layout [level][point][2] coalesced.
// R1 counters: 365 us, 8.6 GB L2->L1 gather traffic ~= 68% of L2 ceiling. Near floor.
__global__ __launch_bounds__(TPB) void k_enc(
    const float* __restrict__ x, const float* __restrict__ emb,
    const float* __restrict__ lw, const float* __restrict__ bmin,
    const float* __restrict__ bmax, float2* __restrict__ ws)
{
    int p = blockIdx.x * TPB + threadIdx.x;
    int l = blockIdx.y;
    float x0 = x[3 * p + 0], x1 = x[3 * p + 1], x2 = x[3 * p + 2];
    float b0 = bmin[0], b1 = bmin[1], b2 = bmin[2];
    float B0 = bmax[0], B1 = bmax[1], B2 = bmax[2];
    float res = c_res[l];
    float gate = 1.0f / (1.0f + expf(-lw[l]));
    const float2* tab = (const float2*)(emb + ((size_t)l << 20));  // 2^19 entries * 2 floats
    float2 r = enc_one(x0, x1, x2, b0, b1, b2, B0, B1, B2, tab, res, gate);
    ws[(size_t)l * NP + p] = r;
}

// Kernel 2 (R2 rewrite): thread n = (point p = n>>3, quad j = n&7).
// Each thread reads ws[2j][p], ws[2j+1][p] and writes out float4 #n.
//  - store: out float4 index == n -> globally contiguous, 1KB/wave, perfect.
//  - load: per instruction, 8 j-clusters x 8 consecutive float2 = 512B/wave,
//    every fetched byte useful (64B-line efficient).
__global__ __launch_bounds__(TPB) void k_tr(
    const float2* __restrict__ ws, float4* __restrict__ out)
{
    size_t n = (size_t)blockIdx.x * TPB + threadIdx.x;   // [0, NP*8)
    size_t p = n >> 3;
    int    j = (int)(n & 7);
    float2 a = ws[(size_t)(2 * j) * NP + p];
    float2 b = ws[(size_t)(2 * j + 1) * NP + p];
    out[n] = make_float4(a.x, a.y, b.x, b.y);
}

// Fallback if ws is too small: thread = (point, group of 4 consecutive levels),
// writes one full 32B sector of out directly.
__global__ __launch_bounds__(TPB) void k_fused(
    const float* __restrict__ x, const float* __restrict__ emb,
    const float* __restrict__ lw, const float* __restrict__ bmin,
    const float* __restrict__ bmax, float* __restrict__ out)
{
    int p = blockIdx.x * TPB + threadIdx.x;
    int g = blockIdx.y;  // 0..3
    float x0 = x[3 * p + 0], x1 = x[3 * p + 1], x2 = x[3 * p + 2];
    float b0 = bmin[0], b1 = bmin[1], b2 = bmin[2];
    float B0 = bmax[0], B1 = bmax[1], B2 = bmax[2];
    float2 o[4];
#pragma unroll
    for (int m = 0; m < 4; ++m) {
        int l = g * 4 + m;
        float res = c_res[l];
        float gate = 1.0f / (1.0f + expf(-lw[l]));
        const float2* tab = (const float2*)(emb + ((size_t)l << 20));
        o[m] = enc_one(x0, x1, x2, b0, b1, b2, B0, B1, B2, tab, res, gate);
    }
    float4* op = (float4*)(out + (size_t)p * 32 + g * 8);
    op[0] = make_float4(o[0].x, o[0].y, o[1].x, o[1].y);
    op[1] = make_float4(o[2].x, o[2].y, o[3].x, o[3].y);
}

extern "C" void kernel_launch(void* const* d_in, const int* in_sizes, int n_in,
                              void* d_out, int out_size, void* d_ws, size_t ws_size,
                              hipStream_t stream) {
    const float* x    = (const float*)d_in[0];
    const float* emb  = (const float*)d_in[1];
    const float* lw   = (const float*)d_in[2];
    const float* bmin = (const float*)d_in[3];
    const float* bmax = (const float*)d_in[4];
    float* out = (float*)d_out;

    const size_t ws_need = (size_t)NL * NP * 2 * sizeof(float);  // 128 MB
    if (ws_size >= ws_need) {
        dim3 grid1(NP / TPB, NL);
        k_enc<<<grid1, TPB, 0, stream>>>(x, emb, lw, bmin, bmax, (float2*)d_ws);
        k_tr<<<(NP * 8) / TPB, TPB, 0, stream>>>((const float2*)d_ws, (float4*)out);
    } else {
        dim3 grid(NP / TPB, 4);
        k_fused<<<grid, TPB, 0, stream>>>(x, emb, lw, bmin, bmax, out);
    }
}

// Round 3
// 554.739 us; speedup vs baseline: 1.0471x; 1.0031x over previous
//
#include <hip/hip_runtime.h>
#include <stdint.h>

// HashEncoder (Instant-NGP / HashNeRF): 1M points, 16 levels, 2 feats, 2^19 table.
// Level-major gather kernel (keeps one 4MiB table per XCD-L2 window) + LDS-tiled
// transpose (fully coalesced global loads AND stores).

static constexpr int NP = 1048576;
static constexpr int NL = 16;
static constexpr int TPB = 256;
static constexpr uint32_t HMASK = (1u << 19) - 1u;

// res_i = floor(16 * b^i), b = f32(exp((ln512-ln16)/15)) = 1.2599210739135742 (> 2^(1/3))
// -> power-of-two levels floor on the UP side: 32/64/128/256/512. Verified R1: absmax 2.4e-7.
__constant__ float c_res[NL] = {16.f, 20.f, 25.f, 32.f, 40.f, 50.f, 64.f, 80.f,
                                101.f, 128.f, 161.f, 203.f, 256.f, 322.f, 406.f, 512.f};

__device__ __forceinline__ float2 enc_one(
    float x0, float x1, float x2,
    float b0, float b1, float b2,
    float B0, float B1, float B2,
    const float2* __restrict__ tab, float res, float gate)
{
    // index path must be bit-exact vs numpy f32: sub/div/floor only (no contraction possible)
    float g0 = (B0 - b0) / res;
    float g1 = (B1 - b1) / res;
    float g2 = (B2 - b2) / res;
    float xc0 = fminf(fmaxf(x0, b0), B0);
    float xc1 = fminf(fmaxf(x1, b1), B1);
    float xc2 = fminf(fmaxf(x2, b2), B2);
    float f0 = floorf((xc0 - b0) / g0);
    float f1 = floorf((xc1 - b1) / g1);
    float f2 = floorf((xc2 - b2) / g2);
    // interpolation weights use RAW x (per reference); rounding here is ~1e-11 on output
    float v0 = f0 * g0 + b0;
    float v1 = f1 * g1 + b1;
    float v2 = f2 * g2 + b2;
    float w0 = (x0 - v0) / ((v0 + g0) - v0);
    float w1 = (x1 - v1) / ((v1 + g1) - v1);
    float w2 = (x2 - v2) / ((v2 + g2) - v2);

    uint32_t u0 = (uint32_t)(int)f0;
    uint32_t u1 = (uint32_t)(int)f1;
    uint32_t u2 = (uint32_t)(int)f2;
    uint32_t ya = u1 * 2654435761u, yb = (u1 + 1u) * 2654435761u;
    uint32_t za = u2 * 805459861u,  zb = (u2 + 1u) * 805459861u;
    uint32_t xa = u0, xb = u0 + 1u;

    // corner index = i*4 + j*2 + k (i on x, j on y, k on z)
    float2 e000 = tab[(xa ^ ya ^ za) & HMASK];
    float2 e001 = tab[(xa ^ ya ^ zb) & HMASK];
    float2 e010 = tab[(xa ^ yb ^ za) & HMASK];
    float2 e011 = tab[(xa ^ yb ^ zb) & HMASK];
    float2 e100 = tab[(xb ^ ya ^ za) & HMASK];
    float2 e101 = tab[(xb ^ ya ^ zb) & HMASK];
    float2 e110 = tab[(xb ^ yb ^ za) & HMASK];
    float2 e111 = tab[(xb ^ yb ^ zb) & HMASK];

    float s0 = 1.f - w0, s1 = 1.f - w1, s2 = 1.f - w2;
    // blend x
    float cx00x = e000.x * s0 + e100.x * w0, cx00y = e000.y * s0 + e100.y * w0;
    float cx01x = e001.x * s0 + e101.x * w0, cx01y = e001.y * s0 + e101.y * w0;
    float cx10x = e010.x * s0 + e110.x * w0, cx10y = e010.y * s0 + e110.y * w0;
    float cx11x = e011.x * s0 + e111.x * w0, cx11y = e011.y * s0 + e111.y * w0;
    // blend y
    float c0x = cx00x * s1 + cx10x * w1, c0y = cx00y * s1 + cx10y * w1;
    float c1x = cx01x * s1 + cx11x * w1, c1y = cx01y * s1 + cx11y * w1;
    // blend z
    float ox = c0x * s2 + c1x * w2;
    float oy = c0y * s2 + c1y * w2;
    return make_float2(ox * gate, oy * gate);
}

// Kernel 1: thread = (point, level). blockIdx.y = level -> level-major dispatch order,
// each XCD L2 holds ~one 4MiB table at a time. ws layout [level][point][2] coalesced.
// R1/R2 counters: 365 us stable; 8.6 GB L2->L1 gather traffic, ~60-70% of the
// L1-line-fill / L2-BW floor (~220-250 us). Structural unless points get sorted.
__global__ __launch_bounds__(TPB) void k_enc(
    const float* __restrict__ x, const float* __restrict__ emb,
    const float* __restrict__ lw, const float* __restrict__ bmin,
    const float* __restrict__ bmax, float2* __restrict__ ws)
{
    int p = blockIdx.x * TPB + threadIdx.x;
    int l = blockIdx.y;
    float x0 = x[3 * p + 0], x1 = x[3 * p + 1], x2 = x[3 * p + 2];
    float b0 = bmin[0], b1 = bmin[1], b2 = bmin[2];
    float B0 = bmax[0], B1 = bmax[1], B2 = bmax[2];
    float res = c_res[l];
    float gate = 1.0f / (1.0f + expf(-lw[l]));
    const float2* tab = (const float2*)(emb + ((size_t)l << 20));  // 2^19 entries * 2 floats
    float2 r = enc_one(x0, x1, x2, b0, b1, b2, B0, B1, B2, tab, res, gate);
    ws[(size_t)l * NP + p] = r;
}

// Kernel 2 (R3: LDS-tiled transpose). Block = 256 threads = 256 points.
// Phase A: 16 coalesced float2 loads (512B/wave each) -> LDS s[256][17]
//   (pad 17: write bank = (2t+2l) mod 32 -> 2-way aliasing = free).
// Phase B: 8 coalesced float4 stores (1KB/wave each), LDS reads <=4-way (~1.58x,
//   negligible vs global traffic).
__global__ __launch_bounds__(TPB) void k_tr(
    const float2* __restrict__ ws, float4* __restrict__ out)
{
    __shared__ float2 s[256][17];
    int t = threadIdx.x;
    size_t p0 = (size_t)blockIdx.x * 256;
#pragma unroll
    for (int l = 0; l < NL; ++l)
        s[t][l] = ws[(size_t)l * NP + p0 + (size_t)t];
    __syncthreads();
#pragma unroll
    for (int k = 0; k < 8; ++k) {
        int n = k * 256 + t;          // 0..2047: float4 index within block tile
        int q = n >> 3;               // local point
        int j = n & 7;                // quad within point
        float2 a = s[q][2 * j];
        float2 b = s[q][2 * j + 1];
        out[p0 * 8 + (size_t)n] = make_float4(a.x, a.y, b.x, b.y);
    }
}

// Fallback if ws is too small: thread = (point, group of 4 consecutive levels),
// writes one full 32B sector of out directly.
__global__ __launch_bounds__(TPB) void k_fused(
    const float* __restrict__ x, const float* __restrict__ emb,
    const float* __restrict__ lw, const float* __restrict__ bmin,
    const float* __restrict__ bmax, float* __restrict__ out)
{
    int p = blockIdx.x * TPB + threadIdx.x;
    int g = blockIdx.y;  // 0..3
    float x0 = x[3 * p + 0], x1 = x[3 * p + 1], x2 = x[3 * p + 2];
    float b0 = bmin[0], b1 = bmin[1], b2 = bmin[2];
    float B0 = bmax[0], B1 = bmax[1], B2 = bmax[2];
    float2 o[4];
#pragma unroll
    for (int m = 0; m < 4; ++m) {
        int l = g * 4 + m;
        float res = c_res[l];
        float gate = 1.0f / (1.0f + expf(-lw[l]));
        const float2* tab = (const float2*)(emb + ((size_t)l << 20));
        o[m] = enc_one(x0, x1, x2, b0, b1, b2, B0, B1, B2, tab, res, gate);
    }
    float4* op = (float4*)(out + (size_t)p * 32 + g * 8);
    op[0] = make_float4(o[0].x, o[0].y, o[1].x, o[1].y);
    op[1] = make_float4(o[2].x, o[2].y, o[3].x, o[3].y);
}

extern "C" void kernel_launch(void* const* d_in, const int* in_sizes, int n_in,
                              void* d_out, int out_size, void* d_ws, size_t ws_size,
                              hipStream_t stream) {
    const float* x    = (const float*)d_in[0];
    const float* emb  = (const float*)d_in[1];
    const float* lw   = (const float*)d_in[2];
    const float* bmin = (const float*)d_in[3];
    const float* bmax = (const float*)d_in[4];
    float* out = (float*)d_out;

    const size_t ws_need = (size_t)NL * NP * 2 * sizeof(float);  // 128 MB
    if (ws_size >= ws_need) {
        dim3 grid1(NP / TPB, NL);
        k_enc<<<grid1, TPB, 0, stream>>>(x, emb, lw, bmin, bmax, (float2*)d_ws);
        k_tr<<<NP / 256, TPB, 0, stream>>>((const float2*)d_ws, (float4*)out);
    } else {
        dim3 grid(NP / TPB, 4);
        k_fused<<<grid, TPB, 0, stream>>>(x, emb, lw, bmin, bmax, out);
    }
}